// Round 3
// baseline (278.730 us; speedup 1.0000x reference)
//
#include <hip/hip_runtime.h>

// x [B=8, C=2, D=16, T=128000] fp32, x_wave [B=8, D=16, T=128000] fp32,
// pad_left = pad_right = 8, WINDOW=8, L=16, k=2.
//
// Identity: output p = seg*8 + dd (per b,c, after pad-trim of 8) gets
//   x[b,c,dd,seg]*w[b,dd,seg] + x[b,c,dd+8,seg-1]*w[b,dd+8,seg-1],
// valid segs 1..T-1.
//
// Round-3 structure: CONTINUOUS STREAM, no LDS, no barriers, no phases.
// Prior rounds falsified load-width / occupancy / MLP-depth / run-length as
// the BW limiter; the surviving theory is read duty cycle (phase-structured
// kernels issue no reads 50-70% of the time). Here every wave issues loads
// continuously, interleaved only with register FMAs and final stores.
//   - thread k owns segs [4k, 4k+4): per d-row 6 float4 loads
//     (w/x0/x1 aligned at t0 for dd<8 term; w/x0/x1 at t0-1, 4B-misaligned,
//     for the dd+8 term), 16 mul+add into 64 output regs. 8 rows unrolled;
//     compiler pipelines loads across rows (~24KB/wave in flight).
//   - stores: 8 aligned contiguous float4 per c (1KB/wave runs).
//   - k=0 masks its two seg-0 quadwords; its t0-1 loads read in-bounds
//     garbage (offset (dd+8)*T-1 > 0) that only feeds masked outputs.

constexpr int B = 8;
constexpr int C = 2;
constexpr int D = 16;
constexpr int T = 128000;

constexpr int SPT = 4;                   // segs per thread
constexpr int TPB = 256;
constexpr int NBX = T / (SPT * TPB);     // 125

__global__ __launch_bounds__(256) void oaa_stream_kernel(
    const float* __restrict__ x,
    const float* __restrict__ xw,
    float* __restrict__ out,
    int S)
{
    const int k  = blockIdx.x * TPB + threadIdx.x;   // 0..31999
    const int t0 = SPT * k;                          // seg base
    const int b  = blockIdx.y;

    const float* __restrict__ xwb = xw + (size_t)b * D * T;
    const float* __restrict__ xb0 = x  + (size_t)b * C * D * T;  // c=0
    const float* __restrict__ xb1 = xb0 + (size_t)D * T;         // c=1

    float o0[32], o1[32];   // o[c][s*8+dd], statically indexed only

#pragma unroll
    for (int dd = 0; dd < 8; ++dd) {
        const size_t ga = (size_t)dd * T + t0;            // aligned
        const size_t gm = (size_t)(dd + 8) * T + t0 - 1;  // 4B-misaligned
        const float4 wa  = *(const float4*)(xwb + ga);
        const float4 wm  = *(const float4*)(xwb + gm);
        const float4 a0  = *(const float4*)(xb0 + ga);
        const float4 m0  = *(const float4*)(xb0 + gm);
        const float4 a1  = *(const float4*)(xb1 + ga);
        const float4 m1  = *(const float4*)(xb1 + gm);
        const float* waf = &wa.x;  const float* wmf = &wm.x;
        const float* a0f = &a0.x;  const float* m0f = &m0.x;
        const float* a1f = &a1.x;  const float* m1f = &m1.x;
#pragma unroll
        for (int s = 0; s < 4; ++s) {
            o0[s * 8 + dd] = waf[s] * a0f[s] + wmf[s] * m0f[s];
            o1[s * 8 + dd] = waf[s] * a1f[s] + wmf[s] * m1f[s];
        }
    }

    // stores: p in [t0*8-8, t0*8+24) per (b,c); aligned float4 runs,
    // consecutive lanes -> consecutive 16B.
    const size_t ob = (size_t)b * C * S;
    float* __restrict__ p0 = out + ob;
    float* __restrict__ p1 = out + ob + S;
    const int base = t0 * 8 - 8;
#pragma unroll
    for (int i = 0; i < 8; ++i) {
        const int p = base + 4 * i;
        if (p >= 0) {                      // false only for k==0, i<2 (seg 0)
            *(float4*)(p0 + p) = make_float4(o0[4 * i], o0[4 * i + 1],
                                             o0[4 * i + 2], o0[4 * i + 3]);
            *(float4*)(p1 + p) = make_float4(o1[4 * i], o1[4 * i + 1],
                                             o1[4 * i + 2], o1[4 * i + 3]);
        }
    }
}

extern "C" void kernel_launch(void* const* d_in, const int* in_sizes, int n_in,
                              void* d_out, int out_size, void* d_ws, size_t ws_size,
                              hipStream_t stream) {
    const float* x  = (const float*)d_in[0];
    const float* xw = (const float*)d_in[1];
    float* out = (float*)d_out;

    const int S = out_size / (B * C);      // 1023992 floats per (b,c)
    dim3 grid(NBX, B);                     // 125 x 8 = 1000 blocks
    oaa_stream_kernel<<<grid, dim3(256), 0, stream>>>(x, xw, out, S);
}

// Round 5
// 251.308 us; speedup vs baseline: 1.1091x; 1.1091x over previous
//
#include <hip/hip_runtime.h>

// x [B=8, C=2, D=16, T=128000] fp32, x_wave [B=8, D=16, T=128000] fp32,
// pad_left = pad_right = 8, WINDOW=8, L=16, k=2.
//
// Identity: output p = seg*8 + dd gets
//   x[b,c,dd,seg]*w[b,dd,seg] + x[b,c,dd+8,seg-1]*w[b,dd+8,seg-1],
// valid segs 1..T-1.
//
// R5 = R1 (best: 86.5us dispatch, FETCH 102MB, WRITE 64MB exactly-minimal)
// + ONE change: non-temporal output stores (MUBUF nt bit), now via native
// ext_vector_type float4 (HIP_vector_type rejected by the builtin in R4).
// Theory: per-dispatch working set = 196.6MB inputs + 65.5MB output = 262MB,
// just over the 256MB Infinity Cache. The write stream's LLC allocation
// evicts ~95MB of input between benchmark dispatches (FETCH=102MB despite
// identical re-read inputs). NT stores bypass LLC allocation -> inputs become
// fully LLC-resident -> read path served from LLC, HBM carries only writes.

constexpr int B = 8;
constexpr int C = 2;
constexpr int D = 16;
constexpr int T = 128000;

constexpr int SEGS  = 256;        // segs per block; T/SEGS = 500 exactly
constexpr int PITCH = 260;        // floats per LDS row: t in [s0-4, s0+256)
constexpr int NBLK  = T / SEGS;   // 500

typedef float v4f __attribute__((ext_vector_type(4)));

__global__ __launch_bounds__(256, 4) void oaa_nt_kernel(
    const float* __restrict__ x,
    const float* __restrict__ xw,
    float* __restrict__ out,
    int S)
{
    __shared__ float P[C][D][PITCH];   // products x*w; tloc = t - (s0-4)

    const int j  = threadIdx.x;
    const int b  = blockIdx.y;
    const int s0 = blockIdx.x * SEGS;

    const float* __restrict__ xwb = xw + (size_t)b * D * T;
    const float* __restrict__ xb0 = x  + (size_t)b * C * D * T;   // c=0
    const float* __restrict__ xb1 = xb0 + (size_t)D * T;          // c=1

    // ---- Phase 1: load + multiply + transposed stage ----
#pragma unroll
    for (int i = 0; i < 4; ++i) {
        const int tau = j + 256 * i;
        const int d   = tau >> 6;                  // 0..15 (wave-uniform)
        const int col = tau & 63;                  // = lane: contiguous 1KB/wave
        const size_t g = (size_t)d * T + (size_t)(s0 + 4 * col);
        const float4 wv  = *(const float4*)(xwb + g);
        const float4 xv0 = *(const float4*)(xb0 + g);
        const float4 xv1 = *(const float4*)(xb1 + g);
        *(float4*)&P[0][d][4 + 4 * col] =
            make_float4(xv0.x * wv.x, xv0.y * wv.y, xv0.z * wv.z, xv0.w * wv.w);
        *(float4*)&P[1][d][4 + 4 * col] =
            make_float4(xv1.x * wv.x, xv1.y * wv.y, xv1.z * wv.z, xv1.w * wv.w);
    }
    // Halo: float4 at t = s0-4 for d in [8,16); only tloc=3 (t=s0-1) is read.
    // Block 0 clamps to t=0; reachable only from seg 0, masked at store.
    if (j < 8) {
        const int d  = j + 8;
        const int th = (s0 >= 4) ? (s0 - 4) : 0;
        const size_t g = (size_t)d * T + (size_t)th;
        const float4 wv  = *(const float4*)(xwb + g);
        const float4 xv0 = *(const float4*)(xb0 + g);
        const float4 xv1 = *(const float4*)(xb1 + g);
        *(float4*)&P[0][d][0] =
            make_float4(xv0.x * wv.x, xv0.y * wv.y, xv0.z * wv.z, xv0.w * wv.w);
        *(float4*)&P[1][d][0] =
            make_float4(xv1.x * wv.x, xv1.y * wv.y, xv1.z * wv.z, xv1.w * wv.w);
    }
    __syncthreads();

    // ---- Phase 2: gather + contiguous NON-TEMPORAL stores ----
    const size_t ob = (size_t)b * C * S;
#pragma unroll
    for (int i = 0; i < 4; ++i) {
        const int sig  = j + 256 * i;              // 0..1023
        const int half = sig & 1;
        const int sloc = (sig >> 1) & (SEGS - 1);
        const int c    = sig >> 9;                 // wave-uniform
        const int seg  = s0 + sloc;
        if (seg != 0) {                            // only block 0 / seg 0 masked
            const int dbase = 4 * half;
            const int ta = sloc + 4;               // term0: t = seg
            const int tb = sloc + 3;               // term1: t = seg-1
            v4f o;
            o.x = P[c][dbase + 0][ta] + P[c][dbase +  8][tb];
            o.y = P[c][dbase + 1][ta] + P[c][dbase +  9][tb];
            o.z = P[c][dbase + 2][ta] + P[c][dbase + 10][tb];
            o.w = P[c][dbase + 3][ta] + P[c][dbase + 11][tb];
            v4f* dst = (v4f*)(out + ob + (size_t)c * S
                              + (size_t)seg * 8 - 8 + dbase);
            __builtin_nontemporal_store(o, dst);   // MUBUF nt: bypass LLC alloc
        }
    }
}

extern "C" void kernel_launch(void* const* d_in, const int* in_sizes, int n_in,
                              void* d_out, int out_size, void* d_ws, size_t ws_size,
                              hipStream_t stream) {
    const float* x  = (const float*)d_in[0];
    const float* xw = (const float*)d_in[1];
    float* out = (float*)d_out;

    const int S = out_size / (B * C);              // 1023992 floats per (b,c)
    dim3 grid(NBLK, B);                            // 500 x 8
    oaa_nt_kernel<<<grid, dim3(256), 0, stream>>>(x, xw, out, S);
}